// Round 7
// baseline (1115.946 us; speedup 1.0000x reference)
//
#include <hip/hip_runtime.h>
#include <hip/hip_bf16.h>
#include <math.h>

// ---- problem constants ----
#define SEQ       4096        // rows per batch
#define DMODEL    2048
#define DINNER    4096
#define DXBC      4224
#define NPROJ     8384
#define NHEADS    64
#define HDIM      64
#define DSTATE    64
#define NCHUNK    64
#define XLD       4352        // merged xBC+dt GEMM width (4224 + 64 dt + 64 pad)

typedef __attribute__((ext_vector_type(8))) _Float16 half8;
typedef __attribute__((ext_vector_type(2))) _Float16 half2v;
typedef __attribute__((ext_vector_type(4))) float floatx4;

__device__ __forceinline__ void async_copy16(void* lds, const void* g) {
  __builtin_amdgcn_global_load_lds(
      (const __attribute__((address_space(1))) unsigned int*)g,
      (__attribute__((address_space(3))) unsigned int*)lds, 16, 0, 0);
}

__device__ __forceinline__ float silu_f(float x) { return x / (1.f + __expf(-x)); }

__device__ __forceinline__ void cvt8(const float* __restrict__ s, _Float16* __restrict__ d) {
  float4 a = *(const float4*)s;
  float4 b = *(const float4*)(s + 4);
  half8 h;
  h[0] = (_Float16)a.x; h[1] = (_Float16)a.y; h[2] = (_Float16)a.z; h[3] = (_Float16)a.w;
  h[4] = (_Float16)b.x; h[5] = (_Float16)b.y; h[6] = (_Float16)b.z; h[7] = (_Float16)b.w;
  *(half8*)d = h;
}

// ---------------- diag: reveal ws_size via absmax if guard trips ----------------
__global__ void diag_kernel(float* out, float v) { out[0] = v; }

// ---------------- generic x8 convert ----------------
__global__ void cvt8_kernel(const float* __restrict__ src, _Float16* __restrict__ dst, int n8) {
  int i = blockIdx.x * 256 + threadIdx.x;
  if (i < n8) cvt8(src + (size_t)i * 8, dst + (size_t)i * 8);
}

// ---------------- fused u + W_in convert ----------------
#define U_N8 (SEQ * DMODEL / 8)          // 1,048,576 half8 groups
__global__ void cvt_in_kernel(const float* __restrict__ u, const float* __restrict__ W_in,
                              _Float16* __restrict__ ubf, _Float16* __restrict__ winbf) {
  int i = blockIdx.x * 256 + threadIdx.x;
  if (i < U_N8) {
    cvt8(u + (size_t)i * 8, ubf + (size_t)i * 8);
  } else {
    int j = i - U_N8;                    // [0, 8448*256)
    int row = j >> 8;
    size_t off = (size_t)j * 8;
    if (row < NPROJ) {
      cvt8(W_in + off, winbf + off);
    } else {
      half8 zz = {};
      *(half8*)(winbf + off) = zz;
    }
  }
}

// ---------------- GEMM (BK=64, 128^2 tile): sliver + small tier ----------------
template <typename OT>
__global__ __launch_bounds__(256) void gemm_bt64(
    const _Float16* __restrict__ A, const _Float16* __restrict__ B,
    OT* __restrict__ C0, OT* __restrict__ C1, int K,
    int ldc0, int ldc1, int ncol0, int tiles_m, int tiles_n) {
  __shared__ __align__(16) _Float16 As[128 * 64];
  __shared__ __align__(16) _Float16 Bs[128 * 64];
  int t = threadIdx.x;
  int nt = tiles_m * tiles_n;
  int id = blockIdx.x;
  int id2 = ((nt & 7) == 0) ? ((id & 7) * (nt >> 3) + (id >> 3)) : id;
  int wband = tiles_m << 2;
  int g = id2 / wband;
  int rm = id2 - g * wband;
  int bw = tiles_n - (g << 2); if (bw > 4) bw = 4;
  int pn = (g << 2) + rm % bw;
  int pm = rm / bw;
  int m0 = pm * 128, n0 = pn * 128;

  int w = t >> 6, lane = t & 63, q = lane >> 4, r = lane & 15;
  int wm = (w >> 1) * 64, wn = (w & 1) * 64;
  int rowoff = lane >> 3;
  int chunkoff = ((lane & 7) ^ rowoff) * 8;
  const _Float16* gA[4];
  const _Float16* gB[4];
#pragma unroll
  for (int i = 0; i < 4; ++i) {
    gA[i] = A + (size_t)(m0 + i * 32 + w * 8 + rowoff) * K + chunkoff;
    gB[i] = B + (size_t)(n0 + i * 32 + w * 8 + rowoff) * K + chunkoff;
  }
  floatx4 acc[4][4] = {};
  for (int k0 = 0; k0 < K; k0 += 64) {
#pragma unroll
    for (int i = 0; i < 4; ++i) {
      async_copy16(As + (i * 32 + w * 8) * 64, gA[i] + k0);
      async_copy16(Bs + (i * 32 + w * 8) * 64, gB[i] + k0);
    }
    __syncthreads();
#pragma unroll
    for (int kk = 0; kk < 64; kk += 32) {
      half8 af[4], bf[4];
#pragma unroll
      for (int im = 0; im < 4; ++im) {
        int R = wm + im * 16 + r;
        af[im] = *(const half8*)&As[R * 64 + ((((kk >> 3) + q) ^ (R & 7)) << 3)];
      }
#pragma unroll
      for (int in = 0; in < 4; ++in) {
        int R = wn + in * 16 + r;
        bf[in] = *(const half8*)&Bs[R * 64 + ((((kk >> 3) + q) ^ (R & 7)) << 3)];
      }
#pragma unroll
      for (int im = 0; im < 4; ++im)
#pragma unroll
        for (int in = 0; in < 4; ++in)
          acc[im][in] =
              __builtin_amdgcn_mfma_f32_16x16x32_f16(af[im], bf[in], acc[im][in], 0, 0, 0);
    }
    __syncthreads();
  }
  OT* Cp = (n0 < ncol0) ? C0 : C1;
  int ldc = (n0 < ncol0) ? ldc0 : ldc1;
  int cb = (n0 < ncol0) ? n0 : n0 - ncol0;
#pragma unroll
  for (int im = 0; im < 4; ++im)
#pragma unroll
    for (int in = 0; in < 4; ++in)
#pragma unroll
      for (int i = 0; i < 4; ++i)
        Cp[(size_t)(m0 + wm + im * 16 + q * 4 + i) * ldc + cb + wn + in * 16 + r] =
            (OT)acc[im][in][i];
}

// ---------------- 256^2 tile, BK=64, read-ahead + base+imm ds_read addressing ---
// Round-6 structure, two waste terms removed:
// 1) B-fragment register reuse: phases (0,kh)/(1,kh) share B frags -> 24
//    ds_read/wave/K-tile instead of 32 (-25% LDS read traffic).
// 2) Zero per-read VALU: the XOR swizzle term depends only on (lane,kh)
//    (R&7 == r16&7), so 8 precomputed base VGPRs + LITERAL offset immediates
//    cover every read. K-loop unrolled x2 so the buffer index is compile-time.
// Ledger per tile: issue 4/8/4/8 reads, waits lgkmcnt(4)/(8)/(4)/(8); one
// lgkm(0)+2 barriers+vmcnt(8) staging block per tile (unchanged from r6).
template <typename OT>
__global__ __launch_bounds__(512, 2) void gemm256(
    const _Float16* __restrict__ A, const _Float16* __restrict__ B,
    OT* __restrict__ C0, OT* __restrict__ C1, int K,
    int ldc0, int ldc1, int ncol0, int tiles_m, int tiles_n) {
  __shared__ __align__(16) _Float16 As[2][256 * 64];
  __shared__ __align__(16) _Float16 Bs[2][256 * 64];
  int t = threadIdx.x;
  int nwg = tiles_m * tiles_n;
  int id = blockIdx.x;
  int wgid = ((nwg & 7) == 0) ? ((id & 7) * (nwg >> 3) + (id >> 3)) : id;
  int wband = tiles_m << 2;
  int g = wgid / wband;
  int rm = wgid - g * wband;
  int bw = tiles_n - (g << 2); if (bw > 4) bw = 4;
  int pn = (g << 2) + rm % bw;
  int pm = rm / bw;
  int m0 = pm * 256, n0 = pn * 256;

  int w = t >> 6, lane = t & 63, q4 = lane >> 4, r16 = lane & 15;
  int srow = lane >> 3;
  int schunk = ((lane & 7) ^ srow) << 3;        // pre-swizzled global source chunk
  const _Float16* gAb = A + (size_t)(m0 + w * 8 + srow) * K + schunk;
  const _Float16* gBb = B + (size_t)(n0 + w * 8 + srow) * K + schunk;
  int Ra = (w >> 2) * 128 + r16;                // wave's A row band (128 rows)
  int Rb = (w & 3) * 64 + r16;                  // wave's B row band (64 rows)

  // --- precomputed LDS read bases (byte addresses, AS3) ---
  unsigned aLds = (unsigned)(unsigned long long)
      (const __attribute__((address_space(3))) void*)(const void*)&As[0][0];
  unsigned bLds = (unsigned)(unsigned long long)
      (const __attribute__((address_space(3))) void*)(const void*)&Bs[0][0];
  int x0 = (q4 ^ (r16 & 7)) << 4;               // swizzle term, kh=0 (bytes)
  int x1 = ((4 + q4) ^ (r16 & 7)) << 4;         // swizzle term, kh=1
  unsigned baseA00 = aLds + Ra * 128 + x0;      // [buf0][kh0]
  unsigned baseA01 = aLds + Ra * 128 + x1;      // [buf0][kh1]
  unsigned baseA10 = baseA00 + 32768;           // [buf1][kh0]
  unsigned baseA11 = baseA01 + 32768;           // [buf1][kh1]
  unsigned baseB00 = bLds + Rb * 128 + x0;
  unsigned baseB01 = bLds + Rb * 128 + x1;
  unsigned baseB10 = baseB00 + 32768;
  unsigned baseB11 = baseB01 + 32768;

  floatx4 acc[8][4] = {};                       // [m-frag][n-frag]
  half8 afA[4], afB[4];                         // A fragment double-buffer
  half8 bfA[4], bfB[4];                         // B frags: kh0 / kh1

#define DSR__(dst, base, off)                                                  \
  asm volatile("ds_read_b128 %0, %1 offset:" #off : "=v"(dst) : "v"(base))
#define DSR(dst, base, off) DSR__(dst, base, off)
#define LDA_LO(afX, bA) { DSR(afX[0], bA, 0);    DSR(afX[1], bA, 2048);        \
                          DSR(afX[2], bA, 4096); DSR(afX[3], bA, 6144); }
#define LDA_HI(afX, bA) { DSR(afX[0], bA, 8192);  DSR(afX[1], bA, 10240);      \
                          DSR(afX[2], bA, 12288); DSR(afX[3], bA, 14336); }
#define LDB4(bfX, bB)   { DSR(bfX[0], bB, 0);    DSR(bfX[1], bB, 2048);        \
                          DSR(bfX[2], bB, 4096); DSR(bfX[3], bB, 6144); }
#define STAGE(buf_, kt_)                                                       \
  {                                                                            \
    _Pragma("unroll") for (int i_ = 0; i_ < 4; ++i_)                           \
        async_copy16(&As[buf_][(i_ * 64 + w * 8) * 64],                        \
                     gAb + (size_t)(i_ * 64) * K + ((kt_) << 6));              \
    _Pragma("unroll") for (int i_ = 0; i_ < 4; ++i_)                           \
        async_copy16(&Bs[buf_][(i_ * 64 + w * 8) * 64],                        \
                     gBb + (size_t)(i_ * 64) * K + ((kt_) << 6));              \
  }
#define MMP(afX, bfX, mh_)                                                     \
  __builtin_amdgcn_s_setprio(1);                                               \
  _Pragma("unroll") for (int mi_ = 0; mi_ < 4; ++mi_)                          \
  _Pragma("unroll") for (int ni_ = 0; ni_ < 4; ++ni_)                          \
      acc[(mh_)*4 + mi_][ni_] = __builtin_amdgcn_mfma_f32_16x16x32_f16(        \
          afX[mi_], bfX[ni_], acc[(mh_)*4 + mi_][ni_], 0, 0, 0);               \
  __builtin_amdgcn_s_setprio(0);
#define BARF() { __builtin_amdgcn_s_barrier(); asm volatile("" ::: "memory"); }
#define WLG(n)                                                                 \
  {                                                                            \
    asm volatile("s_waitcnt lgkmcnt(" #n ")" ::: "memory");                    \
    __builtin_amdgcn_sched_barrier(0);                                         \
  }
// One K-tile, compile-time buffer CUR. Ledger (outstanding lgkm): enter=8.
// p0: +4 (A-hi,kh0) =12, wait<=4 (certifies entry 8: afA+bfA). MM(mh0,kh0).
// p1: +8 (A-lo kh1, B kh1) =12, wait<=8 (certifies afB). MM(mh1,kh0) [bfA reuse].
// p2: +4 (A-hi,kh1) =12, wait<=4 (certifies G3). MM(mh0,kh1).
// p3: wait 0, BAR, stage(kt+2)->CUR, vmcnt(8), BAR, +8 next-tile reads,
//     MM(mh1,kh1) [bfB reuse]. exit=8.
#define TILE(ktv, bA0, bA1, bB1, CURB, bA0n, bB0n)                             \
  {                                                                            \
    LDA_HI(afB, bA0);                                                          \
    WLG(4); MMP(afA, bfA, 0);                                                  \
    LDA_LO(afA, bA1); LDB4(bfB, bB1);                                          \
    WLG(8); MMP(afB, bfA, 1);                                                  \
    LDA_HI(afB, bA1);                                                          \
    WLG(4); MMP(afA, bfB, 0);                                                  \
    WLG(0);                                                                    \
    BARF();                                                                    \
    if ((ktv) + 2 < NT) {                                                      \
      STAGE(CURB, (ktv) + 2);                                                  \
      asm volatile("s_waitcnt vmcnt(8)" ::: "memory");                         \
    } else {                                                                   \
      asm volatile("s_waitcnt vmcnt(0)" ::: "memory");                         \
    }                                                                          \
    BARF();                                                                    \
    if ((ktv) + 1 < NT) { LDA_LO(afA, bA0n); LDB4(bfA, bB0n); }                \
    __builtin_amdgcn_sched_barrier(0);                                         \
    MMP(afB, bfB, 1);                                                          \
  }

  int NT = K >> 6;                               // NT is even for all our shapes
  STAGE(0, 0);
  STAGE(1, 1);
  asm volatile("s_waitcnt vmcnt(8)" ::: "memory");   // tile0 landed; tile1 flies
  BARF();
  LDA_LO(afA, baseA00);
  LDB4(bfA, baseB00);                                // outstanding lgkm = 8

  for (int kt = 0; kt < NT; kt += 2) {
    TILE(kt,     baseA00, baseA01, baseB01, 0, baseA10, baseB10);
    TILE(kt + 1, baseA10, baseA11, baseB11, 1, baseA00, baseB00);
  }

#pragma unroll
  for (int mi = 0; mi < 8; ++mi) {
    int rb = m0 + (w >> 2) * 128 + mi * 16 + q4 * 4;
    OT* Cp = (n0 < ncol0) ? C0 : C1;
    int ldc = (n0 < ncol0) ? ldc0 : ldc1;
    int cb0 = ((n0 < ncol0) ? n0 : n0 - ncol0) + (w & 3) * 64 + r16;
#pragma unroll
    for (int ni = 0; ni < 4; ++ni)
#pragma unroll
      for (int i = 0; i < 4; ++i)
        Cp[(size_t)(rb + i) * ldc + cb0 + ni * 16] = (OT)acc[mi][ni][i];
  }
#undef DSR__
#undef DSR
#undef LDA_LO
#undef LDA_HI
#undef LDB4
#undef STAGE
#undef MMP
#undef BARF
#undef WLG
#undef TILE
}

// ---------------- fused conv1d+silu AND dt-softplus+cumsum ----------------
#define CONVB (SEQ * (DXBC / 2) / 256)   // 33792 conv blocks
__global__ __launch_bounds__(256) void conv_dtscan_kernel(
    const _Float16* __restrict__ xin, const float* __restrict__ conv_w,
    const float* __restrict__ conv_b, _Float16* __restrict__ xcv,
    const float* __restrict__ dt_bias, const float* __restrict__ A_log,
    float* __restrict__ dtp, float* __restrict__ acum, float* __restrict__ chs) {
  int t = threadIdx.x;
  if (blockIdx.x < CONVB) {
    int idx = blockIdx.x * 256 + t;   // over SEQ * (DXBC/2)
    int l = idx / (DXBC / 2);
    int c = (idx - l * (DXBC / 2)) * 2;
    const _Float16* zc = xin + (size_t)l * XLD + c;
    float a0 = conv_b[c], a1 = conv_b[c + 1];
#pragma unroll
    for (int k = 0; k < 4; ++k) {
      int off = k - 3;
      if (l + off >= 0) {
        half2v v = *(const half2v*)(zc + (long)off * XLD);
        a0 += conv_w[c * 4 + k] * (float)v[0];
        a1 += conv_w[c * 4 + 4 + k] * (float)v[1];
      }
    }
    half2v o;
    o[0] = (_Float16)silu_f(a0);
    o[1] = (_Float16)silu_f(a1);
    *(half2v*)(xcv + (size_t)l * DXBC + c) = o;
  } else {
    __shared__ float dAs[64 * 65];      // [l][h] padded
    int c = blockIdx.x - CONVB;
    int h = t & 63;
    const _Float16* dtraw = xin + DXBC;
    float bias = dt_bias[h];
    float negA = -__expf(A_log[h]);
#pragma unroll
    for (int i = 0; i < 16; ++i) {
      int l = i * 4 + (t >> 6);
      int row = c * 64 + l;
      float x = (float)dtraw[(size_t)row * XLD + h] + bias;
      float dtv = (x > 20.f) ? x : log1pf(__expf(x));
      dtp[(size_t)row * 64 + h] = dtv;
      dAs[l * 65 + h] = negA * dtv;
    }
    __syncthreads();
    if (t < 64) {
      float a = 0.f;
      size_t base = ((size_t)c * 64 + t) * 64;
      for (int l = 0; l < 64; ++l) {
        a += dAs[l * 65 + t];
        acum[base + l] = a;
      }
      chs[c * 64 + t] = a;
    }
  }
}

// ---------------- per-chunk states: S[p,n] = sum_l (x*dt)[l,p] * (B*decay)[l,n] ----
__global__ __launch_bounds__(256) void states_kernel(
    const _Float16* __restrict__ xcv, const float* __restrict__ dtp,
    const float* __restrict__ acum, const float* __restrict__ chs,
    _Float16* __restrict__ states) {
  int bid = blockIdx.x;             // h*64 + c
  int c = bid & 63, h = bid >> 6;
  int row0 = c * 64;
  int acbase = (c * 64 + h) * 64;
  __shared__ __align__(16) _Float16 XdT[64 * 72];
  __shared__ __align__(16) _Float16 BdT[64 * 72];
  __shared__ float dec[64];
  int t = threadIdx.x;
  if (t < 64) dec[t] = __expf(chs[acbase >> 6] - acum[acbase + t]);
  __syncthreads();
#pragma unroll
  for (int i = 0; i < 16; ++i) {
    int flat = i * 256 + t;
    int l = flat >> 6, col = flat & 63;
    int grow = row0 + l;
    float dtv = dtp[(size_t)grow * 64 + h];
    float xv = (float)xcv[(size_t)grow * DXBC + h * 64 + col] * dtv;
    XdT[col * 72 + l] = (_Float16)xv;
    float bv = (float)xcv[(size_t)grow * DXBC + DINNER + col] * dec[l];
    BdT[col * 72 + l] = (_Float16)bv;
  }
  __syncthreads();
  int w = t >> 6, lane = t & 63, q = lane >> 4, r = lane & 15;
#pragma unroll
  for (int in = 0; in < 4; ++in) {
    floatx4 a4 = {0.f, 0.f, 0.f, 0.f};
#pragma unroll
    for (int k0 = 0; k0 < 64; k0 += 32) {
      half8 af = *(const half8*)&XdT[(w * 16 + r) * 72 + k0 + q * 8];
      half8 bf = *(const half8*)&BdT[(in * 16 + r) * 72 + k0 + q * 8];
      a4 = __builtin_amdgcn_mfma_f32_16x16x32_f16(af, bf, a4, 0, 0, 0);
    }
#pragma unroll
    for (int i = 0; i < 4; ++i)
      states[((size_t)bid * 64 + (w * 16 + q * 4 + i)) * 64 + in * 16 + r] = (_Float16)a4[i];
  }
}

// ---------------- inter-chunk scan IN PLACE (prefetch-pipelined) ----------------
__global__ __launch_bounds__(256) void scan_kernel(_Float16* __restrict__ states,
                                                   const float* __restrict__ chs) {
  int bid = blockIdx.x;  // h*16 + seg
  int h = bid >> 4, seg = bid & 15;
  size_t base = ((size_t)h * 64) * 4096 + seg * 256 + threadIdx.x;
  float carry = 0.f;
  float s_cur = (float)states[base];
  for (int c = 0; c < 64; ++c) {
    size_t idx = base + (size_t)c * 4096;
    float s_next = (c < 63) ? (float)states[idx + 4096] : 0.f;   // prefetch
    float ec = __expf(chs[c * 64 + h]);
    states[idx] = (_Float16)carry;
    carry = carry * ec + s_cur;
    s_cur = s_next;
  }
}

// ---------------- Y = (CB*Lmat)@Xd + exp(Acum)*(C@Sin^T) + D*x ----------------
__global__ __launch_bounds__(256) void yout_kernel(
    const _Float16* __restrict__ xcv, const float* __restrict__ dtp,
    const float* __restrict__ acum, const _Float16* __restrict__ sin_,
    const float* __restrict__ Dp, _Float16* __restrict__ Y) {
  int bid = blockIdx.x;  // h*64 + c
  int c = bid & 63, h = bid >> 6;
  int row0 = c * 64;
  int acbase = (c * 64 + h) * 64;
  __shared__ __align__(16) _Float16 Cs[64 * 72];
  __shared__ __align__(16) _Float16 Bt[64 * 72];
  __shared__ __align__(16) _Float16 XdT[64 * 72];
  __shared__ __align__(16) _Float16 Ms[64 * 72];
  __shared__ float acs[64];
  int t = threadIdx.x;
  if (t < 64) acs[t] = acum[acbase + t];
#pragma unroll
  for (int i = 0; i < 16; ++i) {
    int flat = i * 256 + t;
    int l = flat >> 6, col = flat & 63;
    int grow = row0 + l;
    const _Float16* rp = xcv + (size_t)grow * DXBC;
    Cs[l * 72 + col] = rp[DINNER + DSTATE + col];
    Bt[l * 72 + col] = rp[DINNER + col];
    float xv = (float)rp[h * 64 + col] * dtp[(size_t)grow * 64 + h];
    XdT[col * 72 + l] = (_Float16)xv;
  }
  __syncthreads();
  int w = t >> 6, lane = t & 63, q = lane >> 4, r = lane & 15;
  int m = w * 16 + r;
#pragma unroll
  for (int in = 0; in < 4; ++in) {
    floatx4 cb = {0.f, 0.f, 0.f, 0.f};
#pragma unroll
    for (int k0 = 0; k0 < 64; k0 += 32) {
      half8 af = *(const half8*)&Cs[m * 72 + k0 + q * 8];
      half8 bf = *(const half8*)&Bt[(in * 16 + r) * 72 + k0 + q * 8];
      cb = __builtin_amdgcn_mfma_f32_16x16x32_f16(af, bf, cb, 0, 0, 0);
    }
#pragma unroll
    for (int i = 0; i < 4; ++i) {
      int l = w * 16 + q * 4 + i;
      int s = in * 16 + r;
      float v = (s <= l) ? cb[i] * __expf(acs[l] - acs[s]) : 0.f;
      Ms[l * 72 + s] = (_Float16)v;
    }
  }
  __syncthreads();
  size_t sbase = (size_t)bid * 4096;
  float Dh = Dp[h];
#pragma unroll
  for (int in = 0; in < 4; ++in) {
    floatx4 acc = {0.f, 0.f, 0.f, 0.f};
#pragma unroll
    for (int k0 = 0; k0 < 64; k0 += 32) {
      half8 af = *(const half8*)&Cs[m * 72 + k0 + q * 8];
      half8 bf = *(const half8*)&sin_[sbase + (size_t)(in * 16 + r) * 64 + k0 + q * 8];
      acc = __builtin_amdgcn_mfma_f32_16x16x32_f16(af, bf, acc, 0, 0, 0);
    }
#pragma unroll
    for (int i = 0; i < 4; ++i) acc[i] *= __expf(acs[w * 16 + q * 4 + i]);
#pragma unroll
    for (int k0 = 0; k0 < 64; k0 += 32) {
      half8 af = *(const half8*)&Ms[m * 72 + k0 + q * 8];
      half8 bf = *(const half8*)&XdT[(in * 16 + r) * 72 + k0 + q * 8];
      acc = __builtin_amdgcn_mfma_f32_16x16x32_f16(af, bf, acc, 0, 0, 0);
    }
#pragma unroll
    for (int i = 0; i < 4; ++i) {
      int l = w * 16 + q * 4 + i;
      int p = in * 16 + r;
      int grow = row0 + l;
      float xv = (float)xcv[(size_t)grow * DXBC + h * 64 + p];
      Y[(size_t)grow * DINNER + h * 64 + p] = (_Float16)(acc[i] + Dh * xv);
    }
  }
}

// ---------------- gated RMSNorm IN PLACE over z (register-resident, half8) ----
__global__ __launch_bounds__(256) void rmsnorm_kernel(const _Float16* __restrict__ Y,
                                                      _Float16* __restrict__ Z,
                                                      const float* __restrict__ norm_w) {
  int row = blockIdx.x;
  const half8* y8 = (const half8*)(Y + (size_t)row * DINNER);
  half8* z8 = (half8*)(Z + (size_t)row * DINNER);
  __shared__ float red[4];
  int t = threadIdx.x;
  float g[16];
  float ss = 0.f;
#pragma unroll
  for (int i = 0; i < 2; ++i) {
    int j = i * 256 + t;
    half8 yv = y8[j];
    half8 zv = z8[j];
#pragma unroll
    for (int e = 0; e < 8; ++e) {
      float gv = (float)yv[e] * silu_f((float)zv[e]);
      g[i * 8 + e] = gv;
      ss += gv * gv;
    }
  }
#pragma unroll
  for (int o = 32; o > 0; o >>= 1) ss += __shfl_down(ss, o, 64);
  if ((t & 63) == 0) red[t >> 6] = ss;
  __syncthreads();
  float rs = rsqrtf((red[0] + red[1] + red[2] + red[3]) / (float)DINNER + 1e-5f);
#pragma unroll
  for (int i = 0; i < 2; ++i) {
    int j = i * 256 + t;
    const float4* w4 = (const float4*)(norm_w + j * 8);
    float4 wa = w4[0], wb = w4[1];
    half8 o;
    o[0] = (_Float16)(g[i * 8 + 0] * rs * wa.x);
    o[1] = (_Float16)(g[i * 8 + 1] * rs * wa.y);
    o[2] = (_Float16)(g[i * 8 + 2] * rs * wa.z);
    o[3] = (_Float16)(g[i * 8 + 3] * rs * wa.w);
    o[4] = (_Float16)(g[i * 8 + 4] * rs * wb.x);
    o[5] = (_Float16)(g[i * 8 + 5] * rs * wb.y);
    o[6] = (_Float16)(g[i * 8 + 6] * rs * wb.z);
    o[7] = (_Float16)(g[i * 8 + 7] * rs * wb.w);
    z8[j] = o;
  }
}

// ---------------- launch ----------------
extern "C" void kernel_launch(void* const* d_in, const int* in_sizes, int n_in,
                              void* d_out, int out_size, void* d_ws, size_t ws_size,
                              hipStream_t stream) {
  const float* u       = (const float*)d_in[0];
  const float* W_in    = (const float*)d_in[1];
  const float* conv_w  = (const float*)d_in[2];
  const float* conv_b  = (const float*)d_in[3];
  const float* dt_bias = (const float*)d_in[4];
  const float* A_log   = (const float*)d_in[5];
  const float* D_param = (const float*)d_in[6];
  const float* norm_w  = (const float*)d_in[7];
  const float* W_out   = (const float*)d_in[8];
  float* out = (float*)d_out;
  char* ws = (char*)d_ws;

  // MID tier: zb holds BOTH batches so the out-projection runs once,
  // batch-stacked (M=8192,N=2048 -> 256 blocks of gemm256). In-projection is
  // ONE 512-block gemm256 over merged cols [0,8192) (z + xBC main, split-C)
  // plus a 64-block gemm_bt64 sliver for cols [8192,8448).
  // winbf aliases xcv (re-converted per batch); ubf aliases states.
  const size_t NEED_MID   = 192954368ULL;
  const size_t NEED_SMALL = 140525568ULL;
  bool big = (ws_size >= NEED_MID);
  if (!big && ws_size < NEED_SMALL) {
    diag_kernel<<<1, 1, 0, stream>>>(out, (float)ws_size);
    return;
  }

  if (big) {
    _Float16* zb     = (_Float16*)(ws + 0);                 // 67,108,864 (both batches)
    _Float16* xbcdtb = (_Float16*)(ws + 67108864ULL);       // 35,651,584 (per batch; Y alias)
    _Float16* xcv    = (_Float16*)(ws + 102760448ULL);      // 34,603,008
    _Float16* winbf  = xcv;                                 // re-converted each batch
    _Float16* states = (_Float16*)(ws + 137363456ULL);      // 33,554,432
    _Float16* ubf    = states;                              // dead before states_kernel
    _Float16* woutbf = (_Float16*)(ws + 170917888ULL);      // 16,777,216 (hoisted)
    float* dtp  = (float*)(ws + 187695104ULL);
    float* acum = (float*)(ws + 188743680ULL);
    float* chs  = (float*)(ws + 189792256ULL);

    cvt8_kernel<<<DMODEL * DINNER / 8 / 256, 256, 0, stream>>>(
        W_out, woutbf, DMODEL * DINNER / 8);

    for (int b = 0; b < 2; ++b) {
      const float* ub = u + (size_t)b * SEQ * DMODEL;
      _Float16* zbb = zb + (size_t)b * SEQ * DINNER;

      cvt_in_kernel<<<U_N8 / 256 + 8448, 256, 0, stream>>>(ub, W_in, ubf, winbf);

      // in-projection main: cols [0,4096)->zbb, [4096,8192)->xbcdt cols [0,4096)
      gemm256<_Float16><<<512, 512, 0, stream>>>(
          ubf, winbf, zbb, xbcdtb, DMODEL, DINNER, XLD, DINNER, 16, 32);
      // sliver: cols [8192,8448) -> xbcdt cols [4096,4352) (incl. dt)
      gemm_bt64<_Float16><<<64, 256, 0, stream>>>(
          ubf, winbf + (size_t)2 * DINNER * DMODEL, xbcdtb + DINNER, xbcdtb + DINNER,
          DMODEL, XLD, XLD, 1 << 30, 32, 2);

      conv_dtscan_kernel<<<CONVB + NCHUNK, 256, 0, stream>>>(
          xbcdtb, conv_w, conv_b, xcv, dt_bias, A_log, dtp, acum, chs);

      states_kernel<<<NHEADS * NCHUNK, 256, 0, stream>>>(xcv, dtp, acum, chs, states);
      scan_kernel<<<NHEADS * 16, 256, 0, stream>>>(states, chs);
      yout_kernel<<<NHEADS * NCHUNK, 256, 0, stream>>>(xcv, dtp, acum, states, D_param,
                                                       xbcdtb /*Y*/);

      rmsnorm_kernel<<<SEQ, 256, 0, stream>>>(xbcdtb, zbb, norm_w);
    }

    // batch-stacked out-projection: M=8192, N=2048, K=4096 -> 32x8 = 256 blocks
    gemm256<float><<<256, 512, 0, stream>>>(
        zb, woutbf, out, out, DINNER, DMODEL, DMODEL, 1 << 30, 32, 8);
  } else {
    // SMALL tier: unchanged R6 layout / per-batch path
    _Float16* zb     = (_Float16*)(ws + 0);
    _Float16* xbcdtb = (_Float16*)(ws + 33554432ULL);
    _Float16* Yb     = xbcdtb;
    _Float16* xcv    = (_Float16*)(ws + 69206016ULL);
    _Float16* winbf  = xcv;
    _Float16* states = (_Float16*)(ws + 103809024ULL);
    _Float16* ubf    = states;
    _Float16* woutbf = states;
    float* dtp  = (float*)(ws + 137363456ULL);
    float* acum = (float*)(ws + 139460608ULL);
    float* chs  = (float*)(ws + 140509184ULL);

    for (int b = 0; b < 2; ++b) {
      const float* ub = u + (size_t)b * SEQ * DMODEL;
      float* outb = out + (size_t)b * SEQ * DMODEL;

      cvt_in_kernel<<<U_N8 / 256 + 8448, 256, 0, stream>>>(ub, W_in, ubf, winbf);
      gemm_bt64<_Float16><<<32 * 66, 256, 0, stream>>>(
          ubf, winbf, zb, xbcdtb, DMODEL, DINNER, XLD, DINNER, 32, 66);
      conv_dtscan_kernel<<<CONVB + NCHUNK, 256, 0, stream>>>(
          xbcdtb, conv_w, conv_b, xcv, dt_bias, A_log, dtp, acum, chs);
      states_kernel<<<NHEADS * NCHUNK, 256, 0, stream>>>(xcv, dtp, acum, chs, states);
      scan_kernel<<<NHEADS * 16, 256, 0, stream>>>(states, chs);
      yout_kernel<<<NHEADS * NCHUNK, 256, 0, stream>>>(xcv, dtp, acum, states, D_param, Yb);
      rmsnorm_kernel<<<SEQ, 256, 0, stream>>>(Yb, zb, norm_w);
      cvt8_kernel<<<DMODEL * DINNER / 8 / 256, 256, 0, stream>>>(
          W_out, woutbf, DMODEL * DINNER / 8);
      gemm_bt64<float><<<32 * 16, 256, 0, stream>>>(
          zb, woutbf, outb, outb, DINNER, DMODEL, DMODEL, 1 << 30, 32, 16);
    }
  }
}

// Round 8
// 1064.977 us; speedup vs baseline: 1.0479x; 1.0479x over previous
//
#include <hip/hip_runtime.h>
#include <hip/hip_bf16.h>
#include <math.h>

// ---- problem constants ----
#define SEQ       4096        // rows per batch
#define DMODEL    2048
#define DINNER    4096
#define DXBC      4224
#define NPROJ     8384
#define NHEADS    64
#define HDIM      64
#define DSTATE    64
#define NCHUNK    64
#define XLD       4352        // merged xBC+dt GEMM width (4224 + 64 dt + 64 pad)

typedef __attribute__((ext_vector_type(8))) _Float16 half8;
typedef __attribute__((ext_vector_type(2))) _Float16 half2v;
typedef __attribute__((ext_vector_type(4))) float floatx4;

__device__ __forceinline__ void async_copy16(void* lds, const void* g) {
  __builtin_amdgcn_global_load_lds(
      (const __attribute__((address_space(1))) unsigned int*)g,
      (__attribute__((address_space(3))) unsigned int*)lds, 16, 0, 0);
}

__device__ __forceinline__ float silu_f(float x) { return x / (1.f + __expf(-x)); }

__device__ __forceinline__ void cvt8(const float* __restrict__ s, _Float16* __restrict__ d) {
  float4 a = *(const float4*)s;
  float4 b = *(const float4*)(s + 4);
  half8 h;
  h[0] = (_Float16)a.x; h[1] = (_Float16)a.y; h[2] = (_Float16)a.z; h[3] = (_Float16)a.w;
  h[4] = (_Float16)b.x; h[5] = (_Float16)b.y; h[6] = (_Float16)b.z; h[7] = (_Float16)b.w;
  *(half8*)d = h;
}

// ---------------- diag: reveal ws_size via absmax if guard trips ----------------
__global__ void diag_kernel(float* out, float v) { out[0] = v; }

// ---------------- generic x8 convert ----------------
__global__ void cvt8_kernel(const float* __restrict__ src, _Float16* __restrict__ dst, int n8) {
  int i = blockIdx.x * 256 + threadIdx.x;
  if (i < n8) cvt8(src + (size_t)i * 8, dst + (size_t)i * 8);
}

// ---------------- fused u + W_in convert ----------------
#define U_N8 (SEQ * DMODEL / 8)          // 1,048,576 half8 groups
__global__ void cvt_in_kernel(const float* __restrict__ u, const float* __restrict__ W_in,
                              _Float16* __restrict__ ubf, _Float16* __restrict__ winbf) {
  int i = blockIdx.x * 256 + threadIdx.x;
  if (i < U_N8) {
    cvt8(u + (size_t)i * 8, ubf + (size_t)i * 8);
  } else {
    int j = i - U_N8;                    // [0, 8448*256)
    int row = j >> 8;
    size_t off = (size_t)j * 8;
    if (row < NPROJ) {
      cvt8(W_in + off, winbf + off);
    } else {
      half8 zz = {};
      *(half8*)(winbf + off) = zz;
    }
  }
}

// ---------------- GEMM (BK=64, 128^2 tile): sliver + small tier ----------------
template <typename OT>
__global__ __launch_bounds__(256) void gemm_bt64(
    const _Float16* __restrict__ A, const _Float16* __restrict__ B,
    OT* __restrict__ C0, OT* __restrict__ C1, int K,
    int ldc0, int ldc1, int ncol0, int tiles_m, int tiles_n) {
  __shared__ __align__(16) _Float16 As[128 * 64];
  __shared__ __align__(16) _Float16 Bs[128 * 64];
  int t = threadIdx.x;
  int nt = tiles_m * tiles_n;
  int id = blockIdx.x;
  int id2 = ((nt & 7) == 0) ? ((id & 7) * (nt >> 3) + (id >> 3)) : id;
  int wband = tiles_m << 2;
  int g = id2 / wband;
  int rm = id2 - g * wband;
  int bw = tiles_n - (g << 2); if (bw > 4) bw = 4;
  int pn = (g << 2) + rm % bw;
  int pm = rm / bw;
  int m0 = pm * 128, n0 = pn * 128;

  int w = t >> 6, lane = t & 63, q = lane >> 4, r = lane & 15;
  int wm = (w >> 1) * 64, wn = (w & 1) * 64;
  int rowoff = lane >> 3;
  int chunkoff = ((lane & 7) ^ rowoff) * 8;
  const _Float16* gA[4];
  const _Float16* gB[4];
#pragma unroll
  for (int i = 0; i < 4; ++i) {
    gA[i] = A + (size_t)(m0 + i * 32 + w * 8 + rowoff) * K + chunkoff;
    gB[i] = B + (size_t)(n0 + i * 32 + w * 8 + rowoff) * K + chunkoff;
  }
  floatx4 acc[4][4] = {};
  for (int k0 = 0; k0 < K; k0 += 64) {
#pragma unroll
    for (int i = 0; i < 4; ++i) {
      async_copy16(As + (i * 32 + w * 8) * 64, gA[i] + k0);
      async_copy16(Bs + (i * 32 + w * 8) * 64, gB[i] + k0);
    }
    __syncthreads();
#pragma unroll
    for (int kk = 0; kk < 64; kk += 32) {
      half8 af[4], bf[4];
#pragma unroll
      for (int im = 0; im < 4; ++im) {
        int R = wm + im * 16 + r;
        af[im] = *(const half8*)&As[R * 64 + ((((kk >> 3) + q) ^ (R & 7)) << 3)];
      }
#pragma unroll
      for (int in = 0; in < 4; ++in) {
        int R = wn + in * 16 + r;
        bf[in] = *(const half8*)&Bs[R * 64 + ((((kk >> 3) + q) ^ (R & 7)) << 3)];
      }
#pragma unroll
      for (int im = 0; im < 4; ++im)
#pragma unroll
        for (int in = 0; in < 4; ++in)
          acc[im][in] =
              __builtin_amdgcn_mfma_f32_16x16x32_f16(af[im], bf[in], acc[im][in], 0, 0, 0);
    }
    __syncthreads();
  }
  OT* Cp = (n0 < ncol0) ? C0 : C1;
  int ldc = (n0 < ncol0) ? ldc0 : ldc1;
  int cb = (n0 < ncol0) ? n0 : n0 - ncol0;
#pragma unroll
  for (int im = 0; im < 4; ++im)
#pragma unroll
    for (int in = 0; in < 4; ++in)
#pragma unroll
      for (int i = 0; i < 4; ++i)
        Cp[(size_t)(m0 + wm + im * 16 + q * 4 + i) * ldc + cb + wn + in * 16 + r] =
            (OT)acc[im][in][i];
}

// ---------------- 256^2 tile, BK=64: faithful m201-style 4-phase quadrant port --
// Phase q of tile T: ALL 8 waves compute one 128x128 C-quadrant (64x32/wave,
// 16 MFMA), K=64 per phase. Operand register reuse across quadrants:
// q0(Alo,Blo): read A-lo(8)+B-lo(4)=12; q1(Alo,Bhi): read B-hi(4);
// q2(Ahi,Bhi): read A-hi(8); q3(Ahi,Blo): 0 reads (bfL kept in regs).
// Staging spread ONE half-tile (2 global_load_lds) per phase into buf[nxt],
// order Alo,Blo,Bhi,Ahi of T+1 (matches first-need order of T+1's phases).
// Counted vmcnt(4) at p0/p1/p3 certifies exactly the half needed 3-4 phases
// later; in-flight never <4 mid-loop. Per phase: {asm ds_reads || stage ||
// vmcnt} -> BAR -> lgkm(0)+sched_barrier -> setprio+16 MFMA -> BAR.
template <typename OT>
__global__ __launch_bounds__(512, 2) void gemm256(
    const _Float16* __restrict__ A, const _Float16* __restrict__ B,
    OT* __restrict__ C0, OT* __restrict__ C1, int K,
    int ldc0, int ldc1, int ncol0, int tiles_m, int tiles_n) {
  __shared__ __align__(16) _Float16 As[2][256 * 64];
  __shared__ __align__(16) _Float16 Bs[2][256 * 64];
  int t = threadIdx.x;
  int nwg = tiles_m * tiles_n;
  int id = blockIdx.x;
  int wgid = ((nwg & 7) == 0) ? ((id & 7) * (nwg >> 3) + (id >> 3)) : id;
  int wband = tiles_m << 2;
  int g = wgid / wband;
  int rm = wgid - g * wband;
  int bw = tiles_n - (g << 2); if (bw > 4) bw = 4;
  int pn = (g << 2) + rm % bw;
  int pm = rm / bw;
  int m0 = pm * 256, n0 = pn * 256;

  int w = t >> 6, lane = t & 63, q4 = lane >> 4, r16 = lane & 15;
  int srow = lane >> 3;
  int schunk = ((lane & 7) ^ srow) << 3;        // pre-swizzled global source chunk
  const _Float16* gAb = A + (size_t)(m0 + w * 8 + srow) * K + schunk;
  const _Float16* gBb = B + (size_t)(n0 + w * 8 + srow) * K + schunk;

  // LDS read bases (byte addrs, AS3). Row stride 128B; A-half stride 16384B;
  // buf stride 32768B. Wave bands: A rows (w>>2)*64 within half; B rows
  // (w&3)*32 within half. Swizzle term depends only on (lane,kh).
  unsigned aLds = (unsigned)(unsigned long long)
      (const __attribute__((address_space(3))) void*)(const void*)&As[0][0];
  unsigned bLds = (unsigned)(unsigned long long)
      (const __attribute__((address_space(3))) void*)(const void*)&Bs[0][0];
  int x0 = (q4 ^ (r16 & 7)) << 4;               // kh=0 swizzle (bytes)
  int x1 = ((4 + q4) ^ (r16 & 7)) << 4;         // kh=1
  unsigned bA00 = aLds + (w >> 2) * 8192 + r16 * 128 + x0;   // buf0,kh0
  unsigned bA01 = aLds + (w >> 2) * 8192 + r16 * 128 + x1;   // buf0,kh1
  unsigned bA10 = bA00 + 32768, bA11 = bA01 + 32768;         // buf1
  unsigned bB00 = bLds + (w & 3) * 4096 + r16 * 128 + x0;
  unsigned bB01 = bLds + (w & 3) * 4096 + r16 * 128 + x1;
  unsigned bB10 = bB00 + 32768, bB11 = bB01 + 32768;

  floatx4 acc[4][4][2] = {};                    // [quadrant][mi][ni]
  half8 af[4][2];                               // live A-half frags [mi][kh]
  half8 bfL[2][2], bfH[2][2];                   // B-lo / B-hi frags [ni][kh]

#define DSR(dst, base, off)                                                    \
  asm volatile("ds_read_b128 %0, %1 offset:" #off : "=v"(dst) : "v"(base))
// A-half reads: pa=0 offsets 0..6144; pa=1 offsets 16384..22528
#define LDA_LOH(b0, b1) { DSR(af[0][0], b0, 0);     DSR(af[0][1], b1, 0);      \
                          DSR(af[1][0], b0, 2048);  DSR(af[1][1], b1, 2048);   \
                          DSR(af[2][0], b0, 4096);  DSR(af[2][1], b1, 4096);   \
                          DSR(af[3][0], b0, 6144);  DSR(af[3][1], b1, 6144); }
#define LDA_HIH(b0, b1) { DSR(af[0][0], b0, 16384); DSR(af[0][1], b1, 16384);  \
                          DSR(af[1][0], b0, 18432); DSR(af[1][1], b1, 18432);  \
                          DSR(af[2][0], b0, 20480); DSR(af[2][1], b1, 20480);  \
                          DSR(af[3][0], b0, 22528); DSR(af[3][1], b1, 22528); }
#define LDB_LOH(bf, b0, b1) { DSR(bf[0][0], b0, 0);     DSR(bf[0][1], b1, 0);  \
                              DSR(bf[1][0], b0, 2048);  DSR(bf[1][1], b1, 2048); }
#define LDB_HIH(bf, b0, b1) { DSR(bf[0][0], b0, 16384); DSR(bf[0][1], b1, 16384); \
                              DSR(bf[1][0], b0, 18432); DSR(bf[1][1], b1, 18432); }
// stage one half-tile (2 loads/thread): H in {0,1}
#define STAGE_A(buf_, H_, kt_)                                                 \
  { _Pragma("unroll") for (int i_ = 0; i_ < 2; ++i_)                           \
        async_copy16(&As[buf_][((H_)*128 + i_ * 64 + w * 8) * 64],             \
                     gAb + (size_t)((H_)*128 + i_ * 64) * K + ((kt_) << 6)); }
#define STAGE_B(buf_, H_, kt_)                                                 \
  { _Pragma("unroll") for (int i_ = 0; i_ < 2; ++i_)                           \
        async_copy16(&Bs[buf_][((H_)*128 + i_ * 64 + w * 8) * 64],             \
                     gBb + (size_t)((H_)*128 + i_ * 64) * K + ((kt_) << 6)); }
#define MM(qd, bf)                                                             \
  __builtin_amdgcn_s_setprio(1);                                               \
  _Pragma("unroll") for (int mi_ = 0; mi_ < 4; ++mi_)                          \
  _Pragma("unroll") for (int ni_ = 0; ni_ < 2; ++ni_)                          \
  _Pragma("unroll") for (int k_ = 0; k_ < 2; ++k_)                             \
      acc[qd][mi_][ni_] = __builtin_amdgcn_mfma_f32_16x16x32_f16(              \
          af[mi_][k_], bf[ni_][k_], acc[qd][mi_][ni_], 0, 0, 0);               \
  __builtin_amdgcn_s_setprio(0);
#define BARF() { __builtin_amdgcn_s_barrier(); asm volatile("" ::: "memory"); }
#define LGKM0()                                                                \
  { asm volatile("s_waitcnt lgkmcnt(0)" ::: "memory");                         \
    __builtin_amdgcn_sched_barrier(0); }
#define VM(n) asm volatile("s_waitcnt vmcnt(" #n ")" ::: "memory")

// One K-tile with compile-time buffer selection. Ledger (2-load half-tiles,
// oldest first), steady entry: [Bhi(T),Ahi(T)] = 4 loads.
// p0: +Alo(T+1)=6, VM(4) certifies Bhi(T)     | reads A-lo(8)+B-lo(4)
// p1: +Blo(T+1)=6, VM(4) certifies Ahi(T)     | reads B-hi(4)
// p2: +Bhi(T+1)=6, no wait                    | reads A-hi(8)
// p3: +Ahi(T+1)=8, VM(4) certifies Alo,Blo(T+1) | no reads (regs reused)
// Tail (kt+1==NT): p0 VM(2), p1 VM(0), p3 none.
#define TILE(ktv, aK0, aK1, bK0, bK1, NXTB)                                    \
  {                                                                            \
    /* ---- p0: quadrant (Alo,Blo) ---- */                                     \
    LDA_LOH(aK0, aK1);                                                         \
    LDB_LOH(bfL, bK0, bK1);                                                    \
    if ((ktv) + 1 < NT) { STAGE_A(NXTB, 0, (ktv) + 1); VM(4); } else VM(2);    \
    BARF(); LGKM0();                                                           \
    MM(0, bfL);                                                                \
    BARF();                                                                    \
    /* ---- p1: quadrant (Alo,Bhi), af reused ---- */                          \
    LDB_HIH(bfH, bK0, bK1);                                                    \
    if ((ktv) + 1 < NT) { STAGE_B(NXTB, 0, (ktv) + 1); VM(4); } else VM(0);    \
    BARF(); LGKM0();                                                           \
    MM(1, bfH);                                                                \
    BARF();                                                                    \
    /* ---- p2: quadrant (Ahi,Bhi), bfH reused ---- */                         \
    LDA_HIH(aK0, aK1);                                                         \
    if ((ktv) + 1 < NT) STAGE_B(NXTB, 1, (ktv) + 1);                           \
    BARF(); LGKM0();                                                           \
    MM(2, bfH);                                                                \
    BARF();                                                                    \
    /* ---- p3: quadrant (Ahi,Blo), af + bfL reused ---- */                    \
    if ((ktv) + 1 < NT) { STAGE_A(NXTB, 1, (ktv) + 1); VM(4); }                \
    BARF();                                                                    \
    __builtin_amdgcn_sched_barrier(0);                                         \
    MM(3, bfL);                                                                \
    BARF();                                                                    \
  }

  int NT = K >> 6;                               // NT even for all our shapes
  // prologue: stage tile0 halves Alo,Blo,Bhi,Ahi; certify Alo,Blo; keep 4 flying
  STAGE_A(0, 0, 0);
  STAGE_B(0, 0, 0);
  STAGE_B(0, 1, 0);
  STAGE_A(0, 1, 0);
  VM(4);
  BARF();

  for (int kt = 0; kt < NT; kt += 2) {
    TILE(kt,     bA00, bA01, bB00, bB01, 1);
    TILE(kt + 1, bA10, bA11, bB10, bB11, 0);
  }

  const int paC[4] = {0, 0, 1, 1};
  const int pbC[4] = {0, 1, 1, 0};
  OT* Cp = (n0 < ncol0) ? C0 : C1;
  int ldc = (n0 < ncol0) ? ldc0 : ldc1;
  int cbase = (n0 < ncol0) ? n0 : n0 - ncol0;
#pragma unroll
  for (int qd = 0; qd < 4; ++qd) {
    int rb = m0 + paC[qd] * 128 + (w >> 2) * 64 + q4 * 4;
    int cb = cbase + pbC[qd] * 128 + (w & 3) * 32 + r16;
#pragma unroll
    for (int mi = 0; mi < 4; ++mi)
#pragma unroll
      for (int ni = 0; ni < 2; ++ni)
#pragma unroll
        for (int i = 0; i < 4; ++i)
          Cp[(size_t)(rb + mi * 16 + i) * ldc + cb + ni * 16] = (OT)acc[qd][mi][ni][i];
  }
#undef DSR
#undef LDA_LOH
#undef LDA_HIH
#undef LDB_LOH
#undef LDB_HIH
#undef STAGE_A
#undef STAGE_B
#undef MM
#undef BARF
#undef LGKM0
#undef VM
#undef TILE
}

// ---------------- fused conv1d+silu AND dt-softplus+cumsum ----------------
#define CONVB (SEQ * (DXBC / 2) / 256)   // 33792 conv blocks
__global__ __launch_bounds__(256) void conv_dtscan_kernel(
    const _Float16* __restrict__ xin, const float* __restrict__ conv_w,
    const float* __restrict__ conv_b, _Float16* __restrict__ xcv,
    const float* __restrict__ dt_bias, const float* __restrict__ A_log,
    float* __restrict__ dtp, float* __restrict__ acum, float* __restrict__ chs) {
  int t = threadIdx.x;
  if (blockIdx.x < CONVB) {
    int idx = blockIdx.x * 256 + t;   // over SEQ * (DXBC/2)
    int l = idx / (DXBC / 2);
    int c = (idx - l * (DXBC / 2)) * 2;
    const _Float16* zc = xin + (size_t)l * XLD + c;
    float a0 = conv_b[c], a1 = conv_b[c + 1];
#pragma unroll
    for (int k = 0; k < 4; ++k) {
      int off = k - 3;
      if (l + off >= 0) {
        half2v v = *(const half2v*)(zc + (long)off * XLD);
        a0 += conv_w[c * 4 + k] * (float)v[0];
        a1 += conv_w[c * 4 + 4 + k] * (float)v[1];
      }
    }
    half2v o;
    o[0] = (_Float16)silu_f(a0);
    o[1] = (_Float16)silu_f(a1);
    *(half2v*)(xcv + (size_t)l * DXBC + c) = o;
  } else {
    __shared__ float dAs[64 * 65];      // [l][h] padded
    int c = blockIdx.x - CONVB;
    int h = t & 63;
    const _Float16* dtraw = xin + DXBC;
    float bias = dt_bias[h];
    float negA = -__expf(A_log[h]);
#pragma unroll
    for (int i = 0; i < 16; ++i) {
      int l = i * 4 + (t >> 6);
      int row = c * 64 + l;
      float x = (float)dtraw[(size_t)row * XLD + h] + bias;
      float dtv = (x > 20.f) ? x : log1pf(__expf(x));
      dtp[(size_t)row * 64 + h] = dtv;
      dAs[l * 65 + h] = negA * dtv;
    }
    __syncthreads();
    if (t < 64) {
      float a = 0.f;
      size_t base = ((size_t)c * 64 + t) * 64;
      for (int l = 0; l < 64; ++l) {
        a += dAs[l * 65 + t];
        acum[base + l] = a;
      }
      chs[c * 64 + t] = a;
    }
  }
}

// ---------------- per-chunk states: S[p,n] = sum_l (x*dt)[l,p] * (B*decay)[l,n] ----
__global__ __launch_bounds__(256) void states_kernel(
    const _Float16* __restrict__ xcv, const float* __restrict__ dtp,
    const float* __restrict__ acum, const float* __restrict__ chs,
    _Float16* __restrict__ states) {
  int bid = blockIdx.x;             // h*64 + c
  int c = bid & 63, h = bid >> 6;
  int row0 = c * 64;
  int acbase = (c * 64 + h) * 64;
  __shared__ __align__(16) _Float16 XdT[64 * 72];
  __shared__ __align__(16) _Float16 BdT[64 * 72];
  __shared__ float dec[64];
  int t = threadIdx.x;
  if (t < 64) dec[t] = __expf(chs[acbase >> 6] - acum[acbase + t]);
  __syncthreads();
#pragma unroll
  for (int i = 0; i < 16; ++i) {
    int flat = i * 256 + t;
    int l = flat >> 6, col = flat & 63;
    int grow = row0 + l;
    float dtv = dtp[(size_t)grow * 64 + h];
    float xv = (float)xcv[(size_t)grow * DXBC + h * 64 + col] * dtv;
    XdT[col * 72 + l] = (_Float16)xv;
    float bv = (float)xcv[(size_t)grow * DXBC + DINNER + col] * dec[l];
    BdT[col * 72 + l] = (_Float16)bv;
  }
  __syncthreads();
  int w = t >> 6, lane = t & 63, q = lane >> 4, r = lane & 15;
#pragma unroll
  for (int in = 0; in < 4; ++in) {
    floatx4 a4 = {0.f, 0.f, 0.f, 0.f};
#pragma unroll
    for (int k0 = 0; k0 < 64; k0 += 32) {
      half8 af = *(const half8*)&XdT[(w * 16 + r) * 72 + k0 + q * 8];
      half8 bf = *(const half8*)&BdT[(in * 16 + r) * 72 + k0 + q * 8];
      a4 = __builtin_amdgcn_mfma_f32_16x16x32_f16(af, bf, a4, 0, 0, 0);
    }
#pragma unroll
    for (int i = 0; i < 4; ++i)
      states[((size_t)bid * 64 + (w * 16 + q * 4 + i)) * 64 + in * 16 + r] = (_Float16)a4[i];
  }
}

// ---------------- inter-chunk scan IN PLACE (prefetch-pipelined) ----------------
__global__ __launch_bounds__(256) void scan_kernel(_Float16* __restrict__ states,
                                                   const float* __restrict__ chs) {
  int bid = blockIdx.x;  // h*16 + seg
  int h = bid >> 4, seg = bid & 15;
  size_t base = ((size_t)h * 64) * 4096 + seg * 256 + threadIdx.x;
  float carry = 0.f;
  float s_cur = (float)states[base];
  for (int c = 0; c < 64; ++c) {
    size_t idx = base + (size_t)c * 4096;
    float s_next = (c < 63) ? (float)states[idx + 4096] : 0.f;   // prefetch
    float ec = __expf(chs[c * 64 + h]);
    states[idx] = (_Float16)carry;
    carry = carry * ec + s_cur;
    s_cur = s_next;
  }
}

// ---------------- Y = (CB*Lmat)@Xd + exp(Acum)*(C@Sin^T) + D*x ----------------
__global__ __launch_bounds__(256) void yout_kernel(
    const _Float16* __restrict__ xcv, const float* __restrict__ dtp,
    const float* __restrict__ acum, const _Float16* __restrict__ sin_,
    const float* __restrict__ Dp, _Float16* __restrict__ Y) {
  int bid = blockIdx.x;  // h*64 + c
  int c = bid & 63, h = bid >> 6;
  int row0 = c * 64;
  int acbase = (c * 64 + h) * 64;
  __shared__ __align__(16) _Float16 Cs[64 * 72];
  __shared__ __align__(16) _Float16 Bt[64 * 72];
  __shared__ __align__(16) _Float16 XdT[64 * 72];
  __shared__ __align__(16) _Float16 Ms[64 * 72];
  __shared__ float acs[64];
  int t = threadIdx.x;
  if (t < 64) acs[t] = acum[acbase + t];
#pragma unroll
  for (int i = 0; i < 16; ++i) {
    int flat = i * 256 + t;
    int l = flat >> 6, col = flat & 63;
    int grow = row0 + l;
    const _Float16* rp = xcv + (size_t)grow * DXBC;
    Cs[l * 72 + col] = rp[DINNER + DSTATE + col];
    Bt[l * 72 + col] = rp[DINNER + col];
    float xv = (float)rp[h * 64 + col] * dtp[(size_t)grow * 64 + h];
    XdT[col * 72 + l] = (_Float16)xv;
  }
  __syncthreads();
  int w = t >> 6, lane = t & 63, q = lane >> 4, r = lane & 15;
  int m = w * 16 + r;
#pragma unroll
  for (int in = 0; in < 4; ++in) {
    floatx4 cb = {0.f, 0.f, 0.f, 0.f};
#pragma unroll
    for (int k0 = 0; k0 < 64; k0 += 32) {
      half8 af = *(const half8*)&Cs[m * 72 + k0 + q * 8];
      half8 bf = *(const half8*)&Bt[(in * 16 + r) * 72 + k0 + q * 8];
      cb = __builtin_amdgcn_mfma_f32_16x16x32_f16(af, bf, cb, 0, 0, 0);
    }
#pragma unroll
    for (int i = 0; i < 4; ++i) {
      int l = w * 16 + q * 4 + i;
      int s = in * 16 + r;
      float v = (s <= l) ? cb[i] * __expf(acs[l] - acs[s]) : 0.f;
      Ms[l * 72 + s] = (_Float16)v;
    }
  }
  __syncthreads();
  size_t sbase = (size_t)bid * 4096;
  float Dh = Dp[h];
#pragma unroll
  for (int in = 0; in < 4; ++in) {
    floatx4 acc = {0.f, 0.f, 0.f, 0.f};
#pragma unroll
    for (int k0 = 0; k0 < 64; k0 += 32) {
      half8 af = *(const half8*)&Cs[m * 72 + k0 + q * 8];
      half8 bf = *(const half8*)&sin_[sbase + (size_t)(in * 16 + r) * 64 + k0 + q * 8];
      acc = __builtin_amdgcn_mfma_f32_16x16x32_f16(af, bf, acc, 0, 0, 0);
    }
#pragma unroll
    for (int i = 0; i < 4; ++i) acc[i] *= __expf(acs[w * 16 + q * 4 + i]);
#pragma unroll
    for (int k0 = 0; k0 < 64; k0 += 32) {
      half8 af = *(const half8*)&Ms[m * 72 + k0 + q * 8];
      half8 bf = *(const half8*)&XdT[(in * 16 + r) * 72 + k0 + q * 8];
      acc = __builtin_amdgcn_mfma_f32_16x16x32_f16(af, bf, acc, 0, 0, 0);
    }
#pragma unroll
    for (int i = 0; i < 4; ++i) {
      int l = w * 16 + q * 4 + i;
      int p = in * 16 + r;
      int grow = row0 + l;
      float xv = (float)xcv[(size_t)grow * DXBC + h * 64 + p];
      Y[(size_t)grow * DINNER + h * 64 + p] = (_Float16)(acc[i] + Dh * xv);
    }
  }
}

// ---------------- gated RMSNorm IN PLACE over z (register-resident, half8) ----
__global__ __launch_bounds__(256) void rmsnorm_kernel(const _Float16* __restrict__ Y,
                                                      _Float16* __restrict__ Z,
                                                      const float* __restrict__ norm_w) {
  int row = blockIdx.x;
  const half8* y8 = (const half8*)(Y + (size_t)row * DINNER);
  half8* z8 = (half8*)(Z + (size_t)row * DINNER);
  __shared__ float red[4];
  int t = threadIdx.x;
  float g[16];
  float ss = 0.f;
#pragma unroll
  for (int i = 0; i < 2; ++i) {
    int j = i * 256 + t;
    half8 yv = y8[j];
    half8 zv = z8[j];
#pragma unroll
    for (int e = 0; e < 8; ++e) {
      float gv = (float)yv[e] * silu_f((float)zv[e]);
      g[i * 8 + e] = gv;
      ss += gv * gv;
    }
  }
#pragma unroll
  for (int o = 32; o > 0; o >>= 1) ss += __shfl_down(ss, o, 64);
  if ((t & 63) == 0) red[t >> 6] = ss;
  __syncthreads();
  float rs = rsqrtf((red[0] + red[1] + red[2] + red[3]) / (float)DINNER + 1e-5f);
#pragma unroll
  for (int i = 0; i < 2; ++i) {
    int j = i * 256 + t;
    const float4* w4 = (const float4*)(norm_w + j * 8);
    float4 wa = w4[0], wb = w4[1];
    half8 o;
    o[0] = (_Float16)(g[i * 8 + 0] * rs * wa.x);
    o[1] = (_Float16)(g[i * 8 + 1] * rs * wa.y);
    o[2] = (_Float16)(g[i * 8 + 2] * rs * wa.z);
    o[3] = (_Float16)(g[i * 8 + 3] * rs * wa.w);
    o[4] = (_Float16)(g[i * 8 + 4] * rs * wb.x);
    o[5] = (_Float16)(g[i * 8 + 5] * rs * wb.y);
    o[6] = (_Float16)(g[i * 8 + 6] * rs * wb.z);
    o[7] = (_Float16)(g[i * 8 + 7] * rs * wb.w);
    z8[j] = o;
  }
}

// ---------------- launch ----------------
extern "C" void kernel_launch(void* const* d_in, const int* in_sizes, int n_in,
                              void* d_out, int out_size, void* d_ws, size_t ws_size,
                              hipStream_t stream) {
  const float* u       = (const float*)d_in[0];
  const float* W_in    = (const float*)d_in[1];
  const float* conv_w  = (const float*)d_in[2];
  const float* conv_b  = (const float*)d_in[3];
  const float* dt_bias = (const float*)d_in[4];
  const float* A_log   = (const float*)d_in[5];
  const float* D_param = (const float*)d_in[6];
  const float* norm_w  = (const float*)d_in[7];
  const float* W_out   = (const float*)d_in[8];
  float* out = (float*)d_out;
  char* ws = (char*)d_ws;

  // MID tier: zb holds BOTH batches so the out-projection runs once,
  // batch-stacked (M=8192,N=2048 -> 256 blocks of gemm256). In-projection is
  // ONE 512-block gemm256 over merged cols [0,8192) (z + xBC main, split-C)
  // plus a 64-block gemm_bt64 sliver for cols [8192,8448).
  // winbf aliases xcv (re-converted per batch); ubf aliases states.
  const size_t NEED_MID   = 192954368ULL;
  const size_t NEED_SMALL = 140525568ULL;
  bool big = (ws_size >= NEED_MID);
  if (!big && ws_size < NEED_SMALL) {
    diag_kernel<<<1, 1, 0, stream>>>(out, (float)ws_size);
    return;
  }

  if (big) {
    _Float16* zb     = (_Float16*)(ws + 0);                 // 67,108,864 (both batches)
    _Float16* xbcdtb = (_Float16*)(ws + 67108864ULL);       // 35,651,584 (per batch; Y alias)
    _Float16* xcv    = (_Float16*)(ws + 102760448ULL);      // 34,603,008
    _Float16* winbf  = xcv;                                 // re-converted each batch
    _Float16* states = (_Float16*)(ws + 137363456ULL);      // 33,554,432
    _Float16* ubf    = states;                              // dead before states_kernel
    _Float16* woutbf = (_Float16*)(ws + 170917888ULL);      // 16,777,216 (hoisted)
    float* dtp  = (float*)(ws + 187695104ULL);
    float* acum = (float*)(ws + 188743680ULL);
    float* chs  = (float*)(ws + 189792256ULL);

    cvt8_kernel<<<DMODEL * DINNER / 8 / 256, 256, 0, stream>>>(
        W_out, woutbf, DMODEL * DINNER / 8);

    for (int b = 0; b < 2; ++b) {
      const float* ub = u + (size_t)b * SEQ * DMODEL;
      _Float16* zbb = zb + (size_t)b * SEQ * DINNER;

      cvt_in_kernel<<<U_N8 / 256 + 8448, 256, 0, stream>>>(ub, W_in, ubf, winbf);

      // in-projection main: cols [0,4096)->zbb, [4096,8192)->xbcdt cols [0,4096)
      gemm256<_Float16><<<512, 512, 0, stream>>>(
          ubf, winbf, zbb, xbcdtb, DMODEL, DINNER, XLD, DINNER, 16, 32);
      // sliver: cols [8192,8448) -> xbcdt cols [4096,4352) (incl. dt)
      gemm_bt64<_Float16><<<64, 256, 0, stream>>>(
          ubf, winbf + (size_t)2 * DINNER * DMODEL, xbcdtb + DINNER, xbcdtb + DINNER,
          DMODEL, XLD, XLD, 1 << 30, 32, 2);

      conv_dtscan_kernel<<<CONVB + NCHUNK, 256, 0, stream>>>(
          xbcdtb, conv_w, conv_b, xcv, dt_bias, A_log, dtp, acum, chs);

      states_kernel<<<NHEADS * NCHUNK, 256, 0, stream>>>(xcv, dtp, acum, chs, states);
      scan_kernel<<<NHEADS * 16, 256, 0, stream>>>(states, chs);
      yout_kernel<<<NHEADS * NCHUNK, 256, 0, stream>>>(xcv, dtp, acum, states, D_param,
                                                       xbcdtb /*Y*/);

      rmsnorm_kernel<<<SEQ, 256, 0, stream>>>(xbcdtb, zbb, norm_w);
    }

    // batch-stacked out-projection: M=8192, N=2048, K=4096 -> 32x8 = 256 blocks
    gemm256<float><<<256, 512, 0, stream>>>(
        zb, woutbf, out, out, DINNER, DMODEL, DMODEL, 1 << 30, 32, 8);
  } else {
    // SMALL tier: unchanged R6 layout / per-batch path
    _Float16* zb     = (_Float16*)(ws + 0);
    _Float16* xbcdtb = (_Float16*)(ws + 33554432ULL);
    _Float16* Yb     = xbcdtb;
    _Float16* xcv    = (_Float16*)(ws + 69206016ULL);
    _Float16* winbf  = xcv;
    _Float16* states = (_Float16*)(ws + 103809024ULL);
    _Float16* ubf    = states;
    _Float16* woutbf = states;
    float* dtp  = (float*)(ws + 137363456ULL);
    float* acum = (float*)(ws + 139460608ULL);
    float* chs  = (float*)(ws + 140509184ULL);

    for (int b = 0; b < 2; ++b) {
      const float* ub = u + (size_t)b * SEQ * DMODEL;
      float* outb = out + (size_t)b * SEQ * DMODEL;

      cvt_in_kernel<<<U_N8 / 256 + 8448, 256, 0, stream>>>(ub, W_in, ubf, winbf);
      gemm_bt64<_Float16><<<32 * 66, 256, 0, stream>>>(
          ubf, winbf, zb, xbcdtb, DMODEL, DINNER, XLD, DINNER, 32, 66);
      conv_dtscan_kernel<<<CONVB + NCHUNK, 256, 0, stream>>>(
          xbcdtb, conv_w, conv_b, xcv, dt_bias, A_log, dtp, acum, chs);
      states_kernel<<<NHEADS * NCHUNK, 256, 0, stream>>>(xcv, dtp, acum, chs, states);
      scan_kernel<<<NHEADS * 16, 256, 0, stream>>>(states, chs);
      yout_kernel<<<NHEADS * NCHUNK, 256, 0, stream>>>(xcv, dtp, acum, states, D_param, Yb);
      rmsnorm_kernel<<<SEQ, 256, 0, stream>>>(Yb, zb, norm_w);
      cvt8_kernel<<<DMODEL * DINNER / 8 / 256, 256, 0, stream>>>(
          W_out, woutbf, DMODEL * DINNER / 8);
      gemm_bt64<float><<<32 * 16, 256, 0, stream>>>(
          zb, woutbf, outb, outb, DINNER, DMODEL, DMODEL, 1 << 30, 32, 16);
    }
  }
}